// Round 1
// baseline (148.870 us; speedup 1.0000x reference)
//
#include <hip/hip_runtime.h>

#define LN_EPS 1e-5f
#define D 768
#define TWO_D 1536

// One wave (64 lanes) per row. Each lane owns 3 float4 of seq and 3 float4 of
// msa (12+12 floats), kept in registers for the whole kernel (single HBM read
// per element). Params (gamma/beta/gate_w) are 24 KB total -> L1/L2 resident.
__global__ __launch_bounds__(256) void fused_gate_kernel(
    const float* __restrict__ seq, const float* __restrict__ msa,
    const float* __restrict__ gamma, const float* __restrict__ beta,
    const float* __restrict__ gate_w, const float* __restrict__ gate_b,
    float* __restrict__ out, int nrows)
{
    const int wave = threadIdx.x >> 6;
    const int lane = threadIdx.x & 63;
    const int row = blockIdx.x * 4 + wave;
    if (row >= nrows) return;

    const float4* seq4 = (const float4*)(seq + (size_t)row * D);
    const float4* msa4 = (const float4*)(msa + (size_t)row * D);

    float4 s[3], m[3];
    #pragma unroll
    for (int j = 0; j < 3; ++j) {
        s[j] = seq4[j * 64 + lane];
        m[j] = msa4[j * 64 + lane];
    }

    // ---- pass 1: sum and sum of squares over the 1536-wide concat row ----
    float sum = 0.f, sumsq = 0.f;
    #pragma unroll
    for (int j = 0; j < 3; ++j) {
        sum   += s[j].x + s[j].y + s[j].z + s[j].w
               + m[j].x + m[j].y + m[j].z + m[j].w;
        sumsq += s[j].x*s[j].x + s[j].y*s[j].y + s[j].z*s[j].z + s[j].w*s[j].w
               + m[j].x*m[j].x + m[j].y*m[j].y + m[j].z*m[j].z + m[j].w*m[j].w;
    }
    #pragma unroll
    for (int off = 32; off > 0; off >>= 1) {
        sum   += __shfl_xor(sum,   off, 64);
        sumsq += __shfl_xor(sumsq, off, 64);
    }
    const float inv_n = 1.f / (float)TWO_D;
    const float mean = sum * inv_n;
    const float var  = fmaxf(sumsq * inv_n - mean * mean, 0.f);
    const float rstd = rsqrtf(var + LN_EPS);

    // ---- pass 2 (registers): normalize + two gate dot-products ----
    const float4* g4  = (const float4*)gamma;
    const float4* b4  = (const float4*)beta;
    const float4* w04 = (const float4*)gate_w;            // row 0 of [2,1536]
    const float4* w14 = (const float4*)(gate_w + TWO_D);  // row 1
    float l0 = 0.f, l1 = 0.f;
    #pragma unroll
    for (int j = 0; j < 3; ++j) {
        const int i4s = j * 64 + lane;        // seq half: h index == i4s (f4 units)
        {
            float4 g = g4[i4s], bb = b4[i4s], w0 = w04[i4s], w1 = w14[i4s];
            float hx = (s[j].x - mean) * rstd * g.x + bb.x;
            float hy = (s[j].y - mean) * rstd * g.y + bb.y;
            float hz = (s[j].z - mean) * rstd * g.z + bb.z;
            float hw = (s[j].w - mean) * rstd * g.w + bb.w;
            l0 += hx * w0.x + hy * w0.y + hz * w0.z + hw * w0.w;
            l1 += hx * w1.x + hy * w1.y + hz * w1.z + hw * w1.w;
        }
        const int i4m = (D / 4) + i4s;        // msa half: offset by 768 floats
        {
            float4 g = g4[i4m], bb = b4[i4m], w0 = w04[i4m], w1 = w14[i4m];
            float hx = (m[j].x - mean) * rstd * g.x + bb.x;
            float hy = (m[j].y - mean) * rstd * g.y + bb.y;
            float hz = (m[j].z - mean) * rstd * g.z + bb.z;
            float hw = (m[j].w - mean) * rstd * g.w + bb.w;
            l0 += hx * w0.x + hy * w0.y + hz * w0.z + hw * w0.w;
            l1 += hx * w1.x + hy * w1.y + hz * w1.z + hw * w1.w;
        }
    }
    #pragma unroll
    for (int off = 32; off > 0; off >>= 1) {
        l0 += __shfl_xor(l0, off, 64);
        l1 += __shfl_xor(l1, off, 64);
    }
    l0 += gate_b[0];
    l1 += gate_b[1];

    // ---- 2-way softmax + blend ----
    const float mx = fmaxf(l0, l1);
    const float e0 = __expf(l0 - mx);
    const float e1 = __expf(l1 - mx);
    const float inv = 1.f / (e0 + e1);
    const float w0s = e0 * inv;
    const float w1s = e1 * inv;

    float4* out4 = (float4*)(out + (size_t)row * D);
    #pragma unroll
    for (int j = 0; j < 3; ++j) {
        float4 o;
        o.x = w0s * s[j].x + w1s * m[j].x;
        o.y = w0s * s[j].y + w1s * m[j].y;
        o.z = w0s * s[j].z + w1s * m[j].z;
        o.w = w0s * s[j].w + w1s * m[j].w;
        out4[j * 64 + lane] = o;
    }
}

extern "C" void kernel_launch(void* const* d_in, const int* in_sizes, int n_in,
                              void* d_out, int out_size, void* d_ws, size_t ws_size,
                              hipStream_t stream) {
    const float* seq    = (const float*)d_in[0];
    const float* msa    = (const float*)d_in[1];
    const float* gamma  = (const float*)d_in[2];
    const float* beta   = (const float*)d_in[3];
    const float* gate_w = (const float*)d_in[4];
    const float* gate_b = (const float*)d_in[5];
    float* out = (float*)d_out;

    const int nrows = in_sizes[0] / D;          // 4*4096 = 16384
    const int blocks = (nrows + 3) / 4;         // 4 rows (waves) per block
    fused_gate_kernel<<<blocks, 256, 0, stream>>>(
        seq, msa, gamma, beta, gate_w, gate_b, out, nrows);
}